// Round 1
// 334.304 us; speedup vs baseline: 1.0777x; 1.0777x over previous
//
#include <hip/hip_runtime.h>
#include <hip/hip_bf16.h>

#define N_NODES 100000
#define FIN 128
#define HID 16
#define NCLS 40
#define NEDGE 3200000
#define NBUCK 391     // ceil(100000/256): 256 dst-nodes per bucket
#define NCHUNK 782    // ceil(NEDGE/4096)
#define XS_LD 132
#define W_LD 132

typedef int v4i __attribute__((ext_vector_type(4)));

__device__ __forceinline__ float4 f4add(float4 a, float4 b) {
  return make_float4(a.x + b.x, a.y + b.y, a.z + b.z, a.w + b.w);
}

// ---------------------------------------------------------------------------
// proj1: xw1 = x @ W1[1], xr1 = x @ root1 (both fp32). (unchanged, ~25 us)
// ---------------------------------------------------------------------------
__global__ __launch_bounds__(256) void proj1_kernel(
    const float* __restrict__ x, const float* __restrict__ W1,
    const float* __restrict__ root1,
    float* __restrict__ xw1, float* __restrict__ xr1) {
  __shared__ float xs[64 * XS_LD];
  __shared__ float WLt[32 * W_LD];

  int tid = threadIdx.x;
  int node0 = blockIdx.x * 64;

  for (int t = tid; t < 32 * FIN; t += 256) {
    int c = t >> 7, i = t & 127;
    WLt[c * W_LD + i] =
        (c < 16) ? W1[FIN * HID + i * HID + c] : root1[i * HID + (c - 16)];
  }
#pragma unroll
  for (int k = 0; k < 8; ++k) {
    int f = k * 256 + tid;
    int r = f >> 5;
    int cw = f & 31;
    float4 v = make_float4(0.f, 0.f, 0.f, 0.f);
    if (node0 + r < N_NODES)
      v = *(const float4*)(x + (size_t)(node0 + r) * FIN + cw * 4);
    *(float4*)(xs + r * XS_LD + cw * 4) = v;
  }
  __syncthreads();

  int tx = tid & 15;
  int ty = tid >> 4;
  const float* w0 = WLt + (2 * tx) * W_LD;
  const float* w1 = w0 + W_LD;
  const float* xrow = xs + (ty * 4) * XS_LD;

  float acc[4][2] = {{0.f, 0.f}, {0.f, 0.f}, {0.f, 0.f}, {0.f, 0.f}};
#pragma unroll 8
  for (int i = 0; i < FIN; i += 4) {
    float4 b0 = *(const float4*)(w0 + i);
    float4 b1v = *(const float4*)(w1 + i);
#pragma unroll
    for (int k = 0; k < 4; ++k) {
      float4 a = *(const float4*)(xrow + k * XS_LD + i);
      acc[k][0] += a.x * b0.x + a.y * b0.y + a.z * b0.z + a.w * b0.w;
      acc[k][1] += a.x * b1v.x + a.y * b1v.y + a.z * b1v.z + a.w * b1v.w;
    }
  }

  int c0 = 2 * tx;
#pragma unroll
  for (int k = 0; k < 4; ++k) {
    int n = node0 + ty * 4 + k;
    if (n < N_NODES) {
      float* dstp = (c0 < 16) ? (xw1 + n * HID + c0) : (xr1 + n * HID + c0 - 16);
      dstp[0] = acc[k][0];
      dstp[1] = acc[k][1];
    }
  }
}

// ---------------------------------------------------------------------------
// histB: bucket histogram (391 counters) with LDS pre-aggregation.
// ---------------------------------------------------------------------------
__global__ __launch_bounds__(256) void histB_kernel(
    const int* __restrict__ dst, int* __restrict__ bcnt) {
  __shared__ int hc[NBUCK];
  for (int t = threadIdx.x; t < NBUCK; t += 256) hc[t] = 0;
  __syncthreads();
  int base = blockIdx.x * 4096;
#pragma unroll
  for (int k = 0; k < 16; ++k) {
    int e = base + k * 256 + threadIdx.x;
    if (e < NEDGE) atomicAdd(&hc[dst[e] >> 8], 1);
  }
  __syncthreads();
  for (int t = threadIdx.x; t < NBUCK; t += 256) {
    int v = hc[t];
    if (v) atomicAdd(&bcnt[t], v);
  }
}

// ---------------------------------------------------------------------------
// scan: exclusive scan of 391 counts -> boff, gcursor; set sentinels.
// ---------------------------------------------------------------------------
__global__ __launch_bounds__(512) void scan_kernel(
    const int* __restrict__ bcnt, int* __restrict__ boff,
    int* __restrict__ gcursor, int* __restrict__ rowptr) {
  __shared__ int s[512];
  int v = (threadIdx.x < NBUCK) ? bcnt[threadIdx.x] : 0;
  s[threadIdx.x] = v;
  __syncthreads();
  for (int off = 1; off < 512; off <<= 1) {
    int t = (threadIdx.x >= off) ? s[threadIdx.x - off] : 0;
    __syncthreads();
    s[threadIdx.x] += t;
    __syncthreads();
  }
  if (threadIdx.x < NBUCK) {
    int e = s[threadIdx.x] - v;
    boff[threadIdx.x] = e;
    gcursor[threadIdx.x] = e;
  }
  if (threadIdx.x == 0) {
    boff[NBUCK] = NEDGE;
    rowptr[N_NODES] = NEDGE;
  }
}

// ---------------------------------------------------------------------------
// partA: multi-split partition, 4096-edge chunks (unchanged).
// rec = src | (dst&255)<<17.
// ---------------------------------------------------------------------------
__global__ __launch_bounds__(256) void partA_kernel(
    const int* __restrict__ src, const int* __restrict__ dst,
    int* __restrict__ gcursor, unsigned* __restrict__ recs) {
  __shared__ int cnt[NBUCK];
  __shared__ int base[NBUCK];
  for (int t = threadIdx.x; t < NBUCK; t += 256) cnt[t] = 0;
  __syncthreads();

  int ebase = blockIdx.x * 4096;
  unsigned recv[16];
  int bk[16];
  int rank[16];
#pragma unroll
  for (int k = 0; k < 16; ++k) {
    int e = ebase + k * 256 + threadIdx.x;
    if (e < NEDGE) {
      int d = dst[e];
      bk[k] = d >> 8;
      recv[k] = (unsigned)src[e] | ((unsigned)(d & 255) << 17);
      rank[k] = atomicAdd(&cnt[bk[k]], 1);
    } else {
      bk[k] = -1;
    }
  }
  __syncthreads();
  for (int t = threadIdx.x; t < NBUCK; t += 256) {
    int cv = cnt[t];
    base[t] = cv ? atomicAdd(&gcursor[t], cv) : 0;
  }
  __syncthreads();
#pragma unroll
  for (int k = 0; k < 16; ++k)
    if (bk[k] >= 0) recs[base[bk[k]] + rank[k]] = recv[k];
}

// ---------------------------------------------------------------------------
// sortB: per-bucket counting sort -> full dst-sorted CSR (rowptr + colsrc).
// ---------------------------------------------------------------------------
__global__ __launch_bounds__(512) void sortB_kernel(
    const int* __restrict__ boff, const unsigned* __restrict__ recs,
    int* __restrict__ rowptr, int* __restrict__ colsrc) {
  __shared__ int hist[256];
  __shared__ int s[256];
  __shared__ int cur[256];
  if (threadIdx.x < 256) hist[threadIdx.x] = 0;
  __syncthreads();

  int b = blockIdx.x;
  int beg = boff[b], end = boff[b + 1];
  for (int j = beg + threadIdx.x; j < end; j += 512)
    atomicAdd(&hist[recs[j] >> 17], 1);
  __syncthreads();

  if (threadIdx.x < 256) s[threadIdx.x] = hist[threadIdx.x];
  __syncthreads();
  for (int off = 1; off < 256; off <<= 1) {
    int t = 0;
    if (threadIdx.x < 256 && threadIdx.x >= off) t = s[threadIdx.x - off];
    __syncthreads();
    if (threadIdx.x < 256) s[threadIdx.x] += t;
    __syncthreads();
  }
  if (threadIdx.x < 256) {
    int excl = s[threadIdx.x] - hist[threadIdx.x];
    int n = b * 256 + threadIdx.x;
    if (n < N_NODES) rowptr[n] = beg + excl;
    cur[threadIdx.x] = excl;
  }
  __syncthreads();

  for (int j = beg + threadIdx.x; j < end; j += 512) {
    unsigned r = recs[j];
    int dl = r >> 17;
    int pos = atomicAdd(&cur[dl], 1);
    colsrc[beg + pos] = (int)(r & 0x1FFFF);
  }
}

// ---------------------------------------------------------------------------
// R10 gather1: 8 lanes/node (q=quarter, p=half). Two halves own alternating
// int4 chunks of the row; hand-unrolled x2 body keeps 8 float4 gathers in
// flight per thread (MLP fix: old version had 20 VGPRs => ~4 outstanding).
// Non-temporal colsrc loads keep the 12.8MB stream out of L2 so the 6.4MB
// val table stays resident. shfl_xor(4) combines halves; p==0 stores.
// Fused mean + xr1 + b1 + ELU epilogue -> h (fp32).
// ---------------------------------------------------------------------------
__global__ __launch_bounds__(256) void gather1_kernel(
    const int* __restrict__ rowptr, const int* __restrict__ colsrc,
    const float4* __restrict__ val4, const float4* __restrict__ xr14,
    const float* __restrict__ b1, float4* __restrict__ h4) {
  int t = blockIdx.x * 256 + threadIdx.x;
  int n = t >> 3;
  if (n >= N_NODES) return;
  int q = t & 3;
  int p = (t >> 2) & 1;
  int beg = rowptr[n], end = rowptr[n + 1];

  float4 acc = make_float4(0.f, 0.f, 0.f, 0.f);
  int bA = (beg + 3) & ~3;
  int eA = end & ~3;
  if (bA > eA) {
    // tiny row: no aligned body, p==0 does everything scalar
    if (p == 0)
      for (int j = beg; j < end; ++j) acc = f4add(acc, val4[colsrc[j] * 4 + q]);
  } else {
    // head by p0, tail by p1 (each <=3 edges)
    if (p == 0) {
      for (int j = beg; j < bA; ++j) acc = f4add(acc, val4[colsrc[j] * 4 + q]);
    } else {
      for (int j = eA; j < end; ++j) acc = f4add(acc, val4[colsrc[j] * 4 + q]);
    }
    // aligned body: chunks of 4 edges, halves interleave (stride 8 per lane)
    float4 acc1 = make_float4(0.f, 0.f, 0.f, 0.f);
    int j = bA + p * 4;
    for (; j + 12 <= eA; j += 16) {
      v4i c0 = __builtin_nontemporal_load((const v4i*)(colsrc + j));
      v4i c1 = __builtin_nontemporal_load((const v4i*)(colsrc + j + 8));
      float4 v0 = val4[c0.x * 4 + q];
      float4 v1 = val4[c0.y * 4 + q];
      float4 v2 = val4[c0.z * 4 + q];
      float4 v3 = val4[c0.w * 4 + q];
      float4 v4v = val4[c1.x * 4 + q];
      float4 v5 = val4[c1.y * 4 + q];
      float4 v6 = val4[c1.z * 4 + q];
      float4 v7 = val4[c1.w * 4 + q];
      acc = f4add(acc, f4add(f4add(v0, v1), f4add(v2, v3)));
      acc1 = f4add(acc1, f4add(f4add(v4v, v5), f4add(v6, v7)));
    }
    for (; j + 4 <= eA; j += 8) {
      v4i c0 = __builtin_nontemporal_load((const v4i*)(colsrc + j));
      float4 v0 = val4[c0.x * 4 + q];
      float4 v1 = val4[c0.y * 4 + q];
      float4 v2 = val4[c0.z * 4 + q];
      float4 v3 = val4[c0.w * 4 + q];
      acc = f4add(acc, f4add(f4add(v0, v1), f4add(v2, v3)));
    }
    acc = f4add(acc, acc1);
  }

  // combine the two halves (lanes differ in bit 2)
  acc.x += __shfl_xor(acc.x, 4);
  acc.y += __shfl_xor(acc.y, 4);
  acc.z += __shfl_xor(acc.z, 4);
  acc.w += __shfl_xor(acc.w, 4);
  if (p) return;

  float inv = 1.0f / fmaxf((float)(end - beg), 1.0f);
  float4 r = xr14[n * 4 + q];
  const float4 bb = *(const float4*)(b1 + q * 4);
  float4 o;
  o.x = acc.x * inv + r.x + bb.x;
  o.y = acc.y * inv + r.y + bb.y;
  o.z = acc.z * inv + r.z + bb.z;
  o.w = acc.w * inv + r.w + bb.w;
  o.x = (o.x > 0.f) ? o.x : expm1f(o.x);
  o.y = (o.y > 0.f) ? o.y : expm1f(o.y);
  o.z = (o.z > 0.f) ? o.z : expm1f(o.z);
  o.w = (o.w > 0.f) ? o.w : expm1f(o.w);
  h4[n * 4 + q] = o;
}

// ---------------------------------------------------------------------------
// R10 gather2: same 8-lane/node structure; writes mean-normalized agg2n.
// ---------------------------------------------------------------------------
__global__ __launch_bounds__(256) void gather2_kernel(
    const int* __restrict__ rowptr, const int* __restrict__ colsrc,
    const float4* __restrict__ val4, float4* __restrict__ agg2n4) {
  int t = blockIdx.x * 256 + threadIdx.x;
  int n = t >> 3;
  if (n >= N_NODES) return;
  int q = t & 3;
  int p = (t >> 2) & 1;
  int beg = rowptr[n], end = rowptr[n + 1];

  float4 acc = make_float4(0.f, 0.f, 0.f, 0.f);
  int bA = (beg + 3) & ~3;
  int eA = end & ~3;
  if (bA > eA) {
    if (p == 0)
      for (int j = beg; j < end; ++j) acc = f4add(acc, val4[colsrc[j] * 4 + q]);
  } else {
    if (p == 0) {
      for (int j = beg; j < bA; ++j) acc = f4add(acc, val4[colsrc[j] * 4 + q]);
    } else {
      for (int j = eA; j < end; ++j) acc = f4add(acc, val4[colsrc[j] * 4 + q]);
    }
    float4 acc1 = make_float4(0.f, 0.f, 0.f, 0.f);
    int j = bA + p * 4;
    for (; j + 12 <= eA; j += 16) {
      v4i c0 = __builtin_nontemporal_load((const v4i*)(colsrc + j));
      v4i c1 = __builtin_nontemporal_load((const v4i*)(colsrc + j + 8));
      float4 v0 = val4[c0.x * 4 + q];
      float4 v1 = val4[c0.y * 4 + q];
      float4 v2 = val4[c0.z * 4 + q];
      float4 v3 = val4[c0.w * 4 + q];
      float4 v4v = val4[c1.x * 4 + q];
      float4 v5 = val4[c1.y * 4 + q];
      float4 v6 = val4[c1.z * 4 + q];
      float4 v7 = val4[c1.w * 4 + q];
      acc = f4add(acc, f4add(f4add(v0, v1), f4add(v2, v3)));
      acc1 = f4add(acc1, f4add(f4add(v4v, v5), f4add(v6, v7)));
    }
    for (; j + 4 <= eA; j += 8) {
      v4i c0 = __builtin_nontemporal_load((const v4i*)(colsrc + j));
      float4 v0 = val4[c0.x * 4 + q];
      float4 v1 = val4[c0.y * 4 + q];
      float4 v2 = val4[c0.z * 4 + q];
      float4 v3 = val4[c0.w * 4 + q];
      acc = f4add(acc, f4add(f4add(v0, v1), f4add(v2, v3)));
    }
    acc = f4add(acc, acc1);
  }

  acc.x += __shfl_xor(acc.x, 4);
  acc.y += __shfl_xor(acc.y, 4);
  acc.z += __shfl_xor(acc.z, 4);
  acc.w += __shfl_xor(acc.w, 4);
  if (p) return;

  float inv = 1.0f / fmaxf((float)(end - beg), 1.0f);
  agg2n4[n * 4 + q] = make_float4(acc.x * inv, acc.y * inv, acc.z * inv,
                                  acc.w * inv);
}

// ---------------------------------------------------------------------------
// out: agg2n @ W2[1] + h @ root2 + b2, log_softmax, fp32 store.
// ---------------------------------------------------------------------------
__global__ __launch_bounds__(256) void out_kernel(
    const float* __restrict__ h, const float* __restrict__ agg2n,
    const float* __restrict__ W2, const float* __restrict__ root2,
    const float* __restrict__ b2v, float* __restrict__ out) {
  __shared__ float Wl[HID * NCLS];
  __shared__ float Rl[HID * NCLS];
  __shared__ float Bl[NCLS];
  for (int i = threadIdx.x; i < HID * NCLS; i += blockDim.x) {
    Wl[i] = W2[HID * NCLS + i];
    Rl[i] = root2[i];
  }
  if (threadIdx.x < NCLS) Bl[threadIdx.x] = b2v[threadIdx.x];
  __syncthreads();

  int n = blockIdx.x * blockDim.x + threadIdx.x;
  if (n >= N_NODES) return;

  float hv[HID], av[HID];
#pragma unroll
  for (int c = 0; c < HID; ++c) {
    hv[c] = h[n * HID + c];
    av[c] = agg2n[n * HID + c];
  }
  float logit[NCLS];
#pragma unroll
  for (int j = 0; j < NCLS; ++j) logit[j] = Bl[j];
  for (int c = 0; c < HID; ++c) {
    float hc = hv[c], ac = av[c];
#pragma unroll
    for (int j = 0; j < NCLS; ++j)
      logit[j] += ac * Wl[c * NCLS + j] + hc * Rl[c * NCLS + j];
  }
  float m = -INFINITY;
#pragma unroll
  for (int j = 0; j < NCLS; ++j) m = fmaxf(m, logit[j]);
  float s = 0.f;
#pragma unroll
  for (int j = 0; j < NCLS; ++j) s += expf(logit[j] - m);
  float lse = m + logf(s);
#pragma unroll
  for (int j = 0; j < NCLS; ++j)
    out[(size_t)n * NCLS + j] = logit[j] - lse;
}

extern "C" void kernel_launch(void* const* d_in, const int* in_sizes, int n_in,
                              void* d_out, int out_size, void* d_ws,
                              size_t ws_size, hipStream_t stream) {
  const float* x = (const float*)d_in[0];
  const int* ei = (const int*)d_in[1];  // (2, E): src row then dst row
  const float* W1 = (const float*)d_in[2];
  const float* root1 = (const float*)d_in[3];
  const float* b1 = (const float*)d_in[4];
  const float* W2 = (const float*)d_in[5];
  const float* root2 = (const float*)d_in[6];
  const float* b2v = (const float*)d_in[7];
  float* out = (float*)d_out;

  const int* src = ei;
  const int* dstp = ei + NEDGE;

  // workspace (bytes), ~38.8 MB:
  // [bcnt 2K][boff 2K][gcursor 2K][rowptr (N+4)*4][recs E*4 (reused as h)]
  // [colsrc E*4][xw1 16N*4 (reused as agg2n)][xr1 16N*4]
  char* w = (char*)d_ws;
  int* bcnt = (int*)w;           w += 2048;
  int* boff = (int*)w;           w += 2048;
  int* gcursor = (int*)w;        w += 2048;
  int* rowptr = (int*)w;         w += (size_t)(N_NODES + 4) * 4;
  unsigned* recs = (unsigned*)w; w += (size_t)NEDGE * 4;
  int* colsrc = (int*)w;         w += (size_t)NEDGE * 4;
  float* xw1 = (float*)w;        w += (size_t)N_NODES * HID * 4;
  float* xr1 = (float*)w;        w += (size_t)N_NODES * HID * 4;
  float* h = (float*)recs;   // recs dead after sortB
  float* agg2n = xw1;        // xw1 dead after gather1

  hipMemsetAsync(bcnt, 0, 2048, stream);

  proj1_kernel<<<(N_NODES + 63) / 64, 256, 0, stream>>>(x, W1, root1, xw1,
                                                        xr1);
  histB_kernel<<<NCHUNK, 256, 0, stream>>>(dstp, bcnt);
  scan_kernel<<<1, 512, 0, stream>>>(bcnt, boff, gcursor, rowptr);
  partA_kernel<<<NCHUNK, 256, 0, stream>>>(src, dstp, gcursor, recs);
  sortB_kernel<<<NBUCK, 512, 0, stream>>>(boff, recs, rowptr, colsrc);
  gather1_kernel<<<(N_NODES * 8 + 255) / 256, 256, 0, stream>>>(
      rowptr, colsrc, (const float4*)xw1, (const float4*)xr1, b1, (float4*)h);
  gather2_kernel<<<(N_NODES * 8 + 255) / 256, 256, 0, stream>>>(
      rowptr, colsrc, (const float4*)h, (float4*)agg2n);
  out_kernel<<<(N_NODES + 255) / 256, 256, 0, stream>>>(h, agg2n, W2, root2,
                                                        b2v, out);
}

// Round 2
// 310.013 us; speedup vs baseline: 1.1621x; 1.0784x over previous
//
#include <hip/hip_runtime.h>
#include <hip/hip_bf16.h>

#define N_NODES 100000
#define FIN 128
#define HID 16
#define NCLS 40
#define NEDGE 3200000
#define NBUCK 391     // ceil(100000/256): 256 dst-nodes per bucket
#define NCHUNK 782    // ceil(NEDGE/4096)
#define XS_LD 132
#define W_LD 132

typedef int v4i __attribute__((ext_vector_type(4)));

__device__ __forceinline__ float4 f4add(float4 a, float4 b) {
  return make_float4(a.x + b.x, a.y + b.y, a.z + b.z, a.w + b.w);
}

// f32 -> bf16 (RNE), hand-rolled to avoid API ambiguity
__device__ __forceinline__ unsigned short f2b(float f) {
  union { float f; unsigned u; } v;
  v.f = f;
  unsigned r = v.u + 0x7FFFu + ((v.u >> 16) & 1u);
  return (unsigned short)(r >> 16);
}

// 4x bf16 -> float4 (shift<<16)
__device__ __forceinline__ float4 b2f4(ushort4 u) {
  union { unsigned u; float f; } a, b, c, d;
  a.u = (unsigned)u.x << 16;
  b.u = (unsigned)u.y << 16;
  c.u = (unsigned)u.z << 16;
  d.u = (unsigned)u.w << 16;
  return make_float4(a.f, b.f, c.f, d.f);
}

// ---------------------------------------------------------------------------
// proj1: xw1b = bf16(x @ W1[1]), xr1 = x @ root1 (fp32).
// xw1 is ONLY consumed by the random gather -> store it bf16 (32B/row) so the
// 3.2MB table fits in a single XCD's 4MiB L2.
// ---------------------------------------------------------------------------
__global__ __launch_bounds__(256) void proj1_kernel(
    const float* __restrict__ x, const float* __restrict__ W1,
    const float* __restrict__ root1,
    unsigned* __restrict__ xw1b, float* __restrict__ xr1) {
  __shared__ float xs[64 * XS_LD];
  __shared__ float WLt[32 * W_LD];

  int tid = threadIdx.x;
  int node0 = blockIdx.x * 64;

  for (int t = tid; t < 32 * FIN; t += 256) {
    int c = t >> 7, i = t & 127;
    WLt[c * W_LD + i] =
        (c < 16) ? W1[FIN * HID + i * HID + c] : root1[i * HID + (c - 16)];
  }
#pragma unroll
  for (int k = 0; k < 8; ++k) {
    int f = k * 256 + tid;
    int r = f >> 5;
    int cw = f & 31;
    float4 v = make_float4(0.f, 0.f, 0.f, 0.f);
    if (node0 + r < N_NODES)
      v = *(const float4*)(x + (size_t)(node0 + r) * FIN + cw * 4);
    *(float4*)(xs + r * XS_LD + cw * 4) = v;
  }
  __syncthreads();

  int tx = tid & 15;
  int ty = tid >> 4;
  const float* w0 = WLt + (2 * tx) * W_LD;
  const float* w1 = w0 + W_LD;
  const float* xrow = xs + (ty * 4) * XS_LD;

  float acc[4][2] = {{0.f, 0.f}, {0.f, 0.f}, {0.f, 0.f}, {0.f, 0.f}};
#pragma unroll 8
  for (int i = 0; i < FIN; i += 4) {
    float4 b0 = *(const float4*)(w0 + i);
    float4 b1v = *(const float4*)(w1 + i);
#pragma unroll
    for (int k = 0; k < 4; ++k) {
      float4 a = *(const float4*)(xrow + k * XS_LD + i);
      acc[k][0] += a.x * b0.x + a.y * b0.y + a.z * b0.z + a.w * b0.w;
      acc[k][1] += a.x * b1v.x + a.y * b1v.y + a.z * b1v.z + a.w * b1v.w;
    }
  }

  int c0 = 2 * tx;
#pragma unroll
  for (int k = 0; k < 4; ++k) {
    int n = node0 + ty * 4 + k;
    if (n < N_NODES) {
      if (c0 < 16) {
        unsigned pk =
            (unsigned)f2b(acc[k][0]) | ((unsigned)f2b(acc[k][1]) << 16);
        xw1b[((size_t)n * HID + c0) >> 1] = pk;
      } else {
        float* dstp = xr1 + (size_t)n * HID + (c0 - 16);
        dstp[0] = acc[k][0];
        dstp[1] = acc[k][1];
      }
    }
  }
}

// ---------------------------------------------------------------------------
// histB: bucket histogram (391 counters) with LDS pre-aggregation.
// ---------------------------------------------------------------------------
__global__ __launch_bounds__(256) void histB_kernel(
    const int* __restrict__ dst, int* __restrict__ bcnt) {
  __shared__ int hc[NBUCK];
  for (int t = threadIdx.x; t < NBUCK; t += 256) hc[t] = 0;
  __syncthreads();
  int base = blockIdx.x * 4096;
#pragma unroll
  for (int k = 0; k < 16; ++k) {
    int e = base + k * 256 + threadIdx.x;
    if (e < NEDGE) atomicAdd(&hc[dst[e] >> 8], 1);
  }
  __syncthreads();
  for (int t = threadIdx.x; t < NBUCK; t += 256) {
    int v = hc[t];
    if (v) atomicAdd(&bcnt[t], v);
  }
}

// ---------------------------------------------------------------------------
// scan: exclusive scan of 391 counts -> boff, gcursor; set sentinels.
// ---------------------------------------------------------------------------
__global__ __launch_bounds__(512) void scan_kernel(
    const int* __restrict__ bcnt, int* __restrict__ boff,
    int* __restrict__ gcursor, int* __restrict__ rowptr) {
  __shared__ int s[512];
  int v = (threadIdx.x < NBUCK) ? bcnt[threadIdx.x] : 0;
  s[threadIdx.x] = v;
  __syncthreads();
  for (int off = 1; off < 512; off <<= 1) {
    int t = (threadIdx.x >= off) ? s[threadIdx.x - off] : 0;
    __syncthreads();
    s[threadIdx.x] += t;
    __syncthreads();
  }
  if (threadIdx.x < NBUCK) {
    int e = s[threadIdx.x] - v;
    boff[threadIdx.x] = e;
    gcursor[threadIdx.x] = e;
  }
  if (threadIdx.x == 0) {
    boff[NBUCK] = NEDGE;
    rowptr[N_NODES] = NEDGE;
  }
}

// ---------------------------------------------------------------------------
// partA: multi-split partition, 4096-edge chunks.
// rec = src | (dst&255)<<17.
// ---------------------------------------------------------------------------
__global__ __launch_bounds__(256) void partA_kernel(
    const int* __restrict__ src, const int* __restrict__ dst,
    int* __restrict__ gcursor, unsigned* __restrict__ recs) {
  __shared__ int cnt[NBUCK];
  __shared__ int base[NBUCK];
  for (int t = threadIdx.x; t < NBUCK; t += 256) cnt[t] = 0;
  __syncthreads();

  int ebase = blockIdx.x * 4096;
  unsigned recv[16];
  int bk[16];
  int rank[16];
#pragma unroll
  for (int k = 0; k < 16; ++k) {
    int e = ebase + k * 256 + threadIdx.x;
    if (e < NEDGE) {
      int d = dst[e];
      bk[k] = d >> 8;
      recv[k] = (unsigned)src[e] | ((unsigned)(d & 255) << 17);
      rank[k] = atomicAdd(&cnt[bk[k]], 1);
    } else {
      bk[k] = -1;
    }
  }
  __syncthreads();
  for (int t = threadIdx.x; t < NBUCK; t += 256) {
    int cv = cnt[t];
    base[t] = cv ? atomicAdd(&gcursor[t], cv) : 0;
  }
  __syncthreads();
#pragma unroll
  for (int k = 0; k < 16; ++k)
    if (bk[k] >= 0) recs[base[bk[k]] + rank[k]] = recv[k];
}

// ---------------------------------------------------------------------------
// sortB: per-bucket counting sort -> full dst-sorted CSR (rowptr + colsrc).
// ---------------------------------------------------------------------------
__global__ __launch_bounds__(512) void sortB_kernel(
    const int* __restrict__ boff, const unsigned* __restrict__ recs,
    int* __restrict__ rowptr, int* __restrict__ colsrc) {
  __shared__ int hist[256];
  __shared__ int s[256];
  __shared__ int cur[256];
  if (threadIdx.x < 256) hist[threadIdx.x] = 0;
  __syncthreads();

  int b = blockIdx.x;
  int beg = boff[b], end = boff[b + 1];
  for (int j = beg + threadIdx.x; j < end; j += 512)
    atomicAdd(&hist[recs[j] >> 17], 1);
  __syncthreads();

  if (threadIdx.x < 256) s[threadIdx.x] = hist[threadIdx.x];
  __syncthreads();
  for (int off = 1; off < 256; off <<= 1) {
    int t = 0;
    if (threadIdx.x < 256 && threadIdx.x >= off) t = s[threadIdx.x - off];
    __syncthreads();
    if (threadIdx.x < 256) s[threadIdx.x] += t;
    __syncthreads();
  }
  if (threadIdx.x < 256) {
    int excl = s[threadIdx.x] - hist[threadIdx.x];
    int n = b * 256 + threadIdx.x;
    if (n < N_NODES) rowptr[n] = beg + excl;
    cur[threadIdx.x] = excl;
  }
  __syncthreads();

  for (int j = beg + threadIdx.x; j < end; j += 512) {
    unsigned r = recs[j];
    int dl = r >> 17;
    int pos = atomicAdd(&cur[dl], 1);
    colsrc[beg + pos] = (int)(r & 0x1FFFF);
  }
}

// ---------------------------------------------------------------------------
// R11 gather1: 8 lanes/node, bf16 val table (ushort4 = 8B per lane, 32B/edge).
// 3.2MB table fits per-XCD L2 -> random gathers become L2 hits.
// Accumulation fp32. Fused mean + xr1 + b1 + ELU -> h (fp32) AND hb (bf16,
// the layer-2 gather table).
// ---------------------------------------------------------------------------
__global__ __launch_bounds__(256) void gather1_kernel(
    const int* __restrict__ rowptr, const int* __restrict__ colsrc,
    const ushort4* __restrict__ valb4, const float4* __restrict__ xr14,
    const float* __restrict__ b1, float4* __restrict__ h4,
    ushort4* __restrict__ hb4) {
  int t = blockIdx.x * 256 + threadIdx.x;
  int n = t >> 3;
  if (n >= N_NODES) return;
  int q = t & 3;
  int p = (t >> 2) & 1;
  int beg = rowptr[n], end = rowptr[n + 1];

  float4 acc = make_float4(0.f, 0.f, 0.f, 0.f);
  int bA = (beg + 3) & ~3;
  int eA = end & ~3;
  if (bA > eA) {
    if (p == 0)
      for (int j = beg; j < end; ++j)
        acc = f4add(acc, b2f4(valb4[colsrc[j] * 4 + q]));
  } else {
    if (p == 0) {
      for (int j = beg; j < bA; ++j)
        acc = f4add(acc, b2f4(valb4[colsrc[j] * 4 + q]));
    } else {
      for (int j = eA; j < end; ++j)
        acc = f4add(acc, b2f4(valb4[colsrc[j] * 4 + q]));
    }
    float4 acc1 = make_float4(0.f, 0.f, 0.f, 0.f);
    int j = bA + p * 4;
    for (; j + 12 <= eA; j += 16) {
      v4i c0 = __builtin_nontemporal_load((const v4i*)(colsrc + j));
      v4i c1 = __builtin_nontemporal_load((const v4i*)(colsrc + j + 8));
      ushort4 v0 = valb4[c0.x * 4 + q];
      ushort4 v1 = valb4[c0.y * 4 + q];
      ushort4 v2 = valb4[c0.z * 4 + q];
      ushort4 v3 = valb4[c0.w * 4 + q];
      ushort4 v4v = valb4[c1.x * 4 + q];
      ushort4 v5 = valb4[c1.y * 4 + q];
      ushort4 v6 = valb4[c1.z * 4 + q];
      ushort4 v7 = valb4[c1.w * 4 + q];
      acc = f4add(acc, f4add(f4add(b2f4(v0), b2f4(v1)),
                             f4add(b2f4(v2), b2f4(v3))));
      acc1 = f4add(acc1, f4add(f4add(b2f4(v4v), b2f4(v5)),
                               f4add(b2f4(v6), b2f4(v7))));
    }
    for (; j + 4 <= eA; j += 8) {
      v4i c0 = __builtin_nontemporal_load((const v4i*)(colsrc + j));
      ushort4 v0 = valb4[c0.x * 4 + q];
      ushort4 v1 = valb4[c0.y * 4 + q];
      ushort4 v2 = valb4[c0.z * 4 + q];
      ushort4 v3 = valb4[c0.w * 4 + q];
      acc = f4add(acc, f4add(f4add(b2f4(v0), b2f4(v1)),
                             f4add(b2f4(v2), b2f4(v3))));
    }
    acc = f4add(acc, acc1);
  }

  acc.x += __shfl_xor(acc.x, 4);
  acc.y += __shfl_xor(acc.y, 4);
  acc.z += __shfl_xor(acc.z, 4);
  acc.w += __shfl_xor(acc.w, 4);
  if (p) return;

  float inv = 1.0f / fmaxf((float)(end - beg), 1.0f);
  float4 r = xr14[n * 4 + q];
  const float4 bb = *(const float4*)(b1 + q * 4);
  float4 o;
  o.x = acc.x * inv + r.x + bb.x;
  o.y = acc.y * inv + r.y + bb.y;
  o.z = acc.z * inv + r.z + bb.z;
  o.w = acc.w * inv + r.w + bb.w;
  o.x = (o.x > 0.f) ? o.x : expm1f(o.x);
  o.y = (o.y > 0.f) ? o.y : expm1f(o.y);
  o.z = (o.z > 0.f) ? o.z : expm1f(o.z);
  o.w = (o.w > 0.f) ? o.w : expm1f(o.w);
  h4[n * 4 + q] = o;
  ushort4 ob;
  ob.x = f2b(o.x);
  ob.y = f2b(o.y);
  ob.z = f2b(o.z);
  ob.w = f2b(o.w);
  hb4[n * 4 + q] = ob;
}

// ---------------------------------------------------------------------------
// R11 gather2: same structure over hb (bf16); writes mean-normalized agg2n.
// ---------------------------------------------------------------------------
__global__ __launch_bounds__(256) void gather2_kernel(
    const int* __restrict__ rowptr, const int* __restrict__ colsrc,
    const ushort4* __restrict__ valb4, float4* __restrict__ agg2n4) {
  int t = blockIdx.x * 256 + threadIdx.x;
  int n = t >> 3;
  if (n >= N_NODES) return;
  int q = t & 3;
  int p = (t >> 2) & 1;
  int beg = rowptr[n], end = rowptr[n + 1];

  float4 acc = make_float4(0.f, 0.f, 0.f, 0.f);
  int bA = (beg + 3) & ~3;
  int eA = end & ~3;
  if (bA > eA) {
    if (p == 0)
      for (int j = beg; j < end; ++j)
        acc = f4add(acc, b2f4(valb4[colsrc[j] * 4 + q]));
  } else {
    if (p == 0) {
      for (int j = beg; j < bA; ++j)
        acc = f4add(acc, b2f4(valb4[colsrc[j] * 4 + q]));
    } else {
      for (int j = eA; j < end; ++j)
        acc = f4add(acc, b2f4(valb4[colsrc[j] * 4 + q]));
    }
    float4 acc1 = make_float4(0.f, 0.f, 0.f, 0.f);
    int j = bA + p * 4;
    for (; j + 12 <= eA; j += 16) {
      v4i c0 = __builtin_nontemporal_load((const v4i*)(colsrc + j));
      v4i c1 = __builtin_nontemporal_load((const v4i*)(colsrc + j + 8));
      ushort4 v0 = valb4[c0.x * 4 + q];
      ushort4 v1 = valb4[c0.y * 4 + q];
      ushort4 v2 = valb4[c0.z * 4 + q];
      ushort4 v3 = valb4[c0.w * 4 + q];
      ushort4 v4v = valb4[c1.x * 4 + q];
      ushort4 v5 = valb4[c1.y * 4 + q];
      ushort4 v6 = valb4[c1.z * 4 + q];
      ushort4 v7 = valb4[c1.w * 4 + q];
      acc = f4add(acc, f4add(f4add(b2f4(v0), b2f4(v1)),
                             f4add(b2f4(v2), b2f4(v3))));
      acc1 = f4add(acc1, f4add(f4add(b2f4(v4v), b2f4(v5)),
                               f4add(b2f4(v6), b2f4(v7))));
    }
    for (; j + 4 <= eA; j += 8) {
      v4i c0 = __builtin_nontemporal_load((const v4i*)(colsrc + j));
      ushort4 v0 = valb4[c0.x * 4 + q];
      ushort4 v1 = valb4[c0.y * 4 + q];
      ushort4 v2 = valb4[c0.z * 4 + q];
      ushort4 v3 = valb4[c0.w * 4 + q];
      acc = f4add(acc, f4add(f4add(b2f4(v0), b2f4(v1)),
                             f4add(b2f4(v2), b2f4(v3))));
    }
    acc = f4add(acc, acc1);
  }

  acc.x += __shfl_xor(acc.x, 4);
  acc.y += __shfl_xor(acc.y, 4);
  acc.z += __shfl_xor(acc.z, 4);
  acc.w += __shfl_xor(acc.w, 4);
  if (p) return;

  float inv = 1.0f / fmaxf((float)(end - beg), 1.0f);
  agg2n4[n * 4 + q] = make_float4(acc.x * inv, acc.y * inv, acc.z * inv,
                                  acc.w * inv);
}

// ---------------------------------------------------------------------------
// out: agg2n @ W2[1] + h @ root2 + b2, log_softmax, fp32 store.
// ---------------------------------------------------------------------------
__global__ __launch_bounds__(256) void out_kernel(
    const float* __restrict__ h, const float* __restrict__ agg2n,
    const float* __restrict__ W2, const float* __restrict__ root2,
    const float* __restrict__ b2v, float* __restrict__ out) {
  __shared__ float Wl[HID * NCLS];
  __shared__ float Rl[HID * NCLS];
  __shared__ float Bl[NCLS];
  for (int i = threadIdx.x; i < HID * NCLS; i += blockDim.x) {
    Wl[i] = W2[HID * NCLS + i];
    Rl[i] = root2[i];
  }
  if (threadIdx.x < NCLS) Bl[threadIdx.x] = b2v[threadIdx.x];
  __syncthreads();

  int n = blockIdx.x * blockDim.x + threadIdx.x;
  if (n >= N_NODES) return;

  float hv[HID], av[HID];
#pragma unroll
  for (int c = 0; c < HID; ++c) {
    hv[c] = h[n * HID + c];
    av[c] = agg2n[n * HID + c];
  }
  float logit[NCLS];
#pragma unroll
  for (int j = 0; j < NCLS; ++j) logit[j] = Bl[j];
  for (int c = 0; c < HID; ++c) {
    float hc = hv[c], ac = av[c];
#pragma unroll
    for (int j = 0; j < NCLS; ++j)
      logit[j] += ac * Wl[c * NCLS + j] + hc * Rl[c * NCLS + j];
  }
  float m = -INFINITY;
#pragma unroll
  for (int j = 0; j < NCLS; ++j) m = fmaxf(m, logit[j]);
  float s = 0.f;
#pragma unroll
  for (int j = 0; j < NCLS; ++j) s += expf(logit[j] - m);
  float lse = m + logf(s);
#pragma unroll
  for (int j = 0; j < NCLS; ++j)
    out[(size_t)n * NCLS + j] = logit[j] - lse;
}

extern "C" void kernel_launch(void* const* d_in, const int* in_sizes, int n_in,
                              void* d_out, int out_size, void* d_ws,
                              size_t ws_size, hipStream_t stream) {
  const float* x = (const float*)d_in[0];
  const int* ei = (const int*)d_in[1];  // (2, E): src row then dst row
  const float* W1 = (const float*)d_in[2];
  const float* root1 = (const float*)d_in[3];
  const float* b1 = (const float*)d_in[4];
  const float* W2 = (const float*)d_in[5];
  const float* root2 = (const float*)d_in[6];
  const float* b2v = (const float*)d_in[7];
  float* out = (float*)d_out;

  const int* src = ei;
  const int* dstp = ei + NEDGE;

  // workspace (bytes), ~38.8 MB:
  // [bcnt 2K][boff 2K][gcursor 2K][rowptr (N+4)*4]
  // [recs E*4  (lower half reused as h fp32, upper half as agg2n fp32)]
  // [colsrc E*4][xw1b 16N*2][xr1 16N*4][hb 16N*2]
  char* w = (char*)d_ws;
  int* bcnt = (int*)w;           w += 2048;
  int* boff = (int*)w;           w += 2048;
  int* gcursor = (int*)w;        w += 2048;
  int* rowptr = (int*)w;         w += (size_t)(N_NODES + 4) * 4;
  unsigned* recs = (unsigned*)w; w += (size_t)NEDGE * 4;
  int* colsrc = (int*)w;         w += (size_t)NEDGE * 4;
  unsigned* xw1b = (unsigned*)w; w += (size_t)N_NODES * HID * 2;
  float* xr1 = (float*)w;        w += (size_t)N_NODES * HID * 4;
  unsigned short* hb = (unsigned short*)w; w += (size_t)N_NODES * HID * 2;

  float* h = (float*)recs;  // recs dead after sortB; h = 6.4MB (half of recs)
  float* agg2n = (float*)((char*)recs + (size_t)N_NODES * HID * 4);

  hipMemsetAsync(bcnt, 0, 2048, stream);

  proj1_kernel<<<(N_NODES + 63) / 64, 256, 0, stream>>>(x, W1, root1, xw1b,
                                                        xr1);
  histB_kernel<<<NCHUNK, 256, 0, stream>>>(dstp, bcnt);
  scan_kernel<<<1, 512, 0, stream>>>(bcnt, boff, gcursor, rowptr);
  partA_kernel<<<NCHUNK, 256, 0, stream>>>(src, dstp, gcursor, recs);
  sortB_kernel<<<NBUCK, 512, 0, stream>>>(boff, recs, rowptr, colsrc);
  gather1_kernel<<<(N_NODES * 8 + 255) / 256, 256, 0, stream>>>(
      rowptr, colsrc, (const ushort4*)xw1b, (const float4*)xr1, b1, (float4*)h,
      (ushort4*)hb);
  gather2_kernel<<<(N_NODES * 8 + 255) / 256, 256, 0, stream>>>(
      rowptr, colsrc, (const ushort4*)hb, (float4*)agg2n);
  out_kernel<<<(N_NODES + 255) / 256, 256, 0, stream>>>(h, agg2n, W2, root2,
                                                        b2v, out);
}

// Round 3
// 303.031 us; speedup vs baseline: 1.1889x; 1.0230x over previous
//
#include <hip/hip_runtime.h>
#include <hip/hip_bf16.h>

#define N_NODES 100000
#define FIN 128
#define HID 16
#define NCLS 40
#define NEDGE 3200000
#define NBUCK 391     // ceil(100000/256): 256 dst-nodes per bucket
#define NCHUNK 782    // ceil(NEDGE/4096)
#define W_ROW 144     // swizzled W row stride (floats): 128 + 4-float pad per 32-k block

typedef int v4i __attribute__((ext_vector_type(4)));

__device__ __forceinline__ float4 f4add(float4 a, float4 b) {
  return make_float4(a.x + b.x, a.y + b.y, a.z + b.z, a.w + b.w);
}

// f32 -> bf16 (RNE)
__device__ __forceinline__ unsigned short f2b(float f) {
  union { float f; unsigned u; } v;
  v.f = f;
  unsigned r = v.u + 0x7FFFu + ((v.u >> 16) & 1u);
  return (unsigned short)(r >> 16);
}

// 4x bf16 -> float4 (shift<<16)
__device__ __forceinline__ float4 b2f4(ushort4 u) {
  union { unsigned u; float f; } a, b, c, d;
  a.u = (unsigned)u.x << 16;
  b.u = (unsigned)u.y << 16;
  c.u = (unsigned)u.z << 16;
  d.u = (unsigned)u.w << 16;
  return make_float4(a.f, b.f, c.f, d.f);
}

// ---------------------------------------------------------------------------
// R12 proj1: 4 lanes per node, no x LDS staging (coalesced 128B/lane register
// loads), W in bank-swizzled LDS (16 distinct banks per read instr), shfl_xor
// butterfly + static-index stores. Fixes R11's 23% occupancy (50.7KB LDS) and
// 1.6M bank conflicts.
// Wcat col c: c<16 -> W1[1][:,c] (output xw1b bf16), else root1[:,c-16] (xr1).
// ---------------------------------------------------------------------------
__global__ __launch_bounds__(256) void proj1_kernel(
    const float* __restrict__ x, const float* __restrict__ W1,
    const float* __restrict__ root1,
    unsigned* __restrict__ xw1b, float* __restrict__ xr1) {
  __shared__ float Wl[32 * W_ROW];  // [col][k swizzled]: 18.4 KB

  int tid = threadIdx.x;
  for (int t = tid; t < 32 * FIN; t += 256) {
    int c = t >> 7, k = t & 127;
    float v = (c < 16) ? W1[FIN * HID + k * HID + c] : root1[k * HID + (c - 16)];
    Wl[c * W_ROW + k + ((k >> 5) << 2)] = v;  // +4-float pad per 32-k block
  }
  __syncthreads();

  int n = blockIdx.x * 64 + (tid >> 2);
  int j = tid & 3;  // k-quarter: k in [32j, 32j+32)
  bool live = (n < N_NODES);

  float4 xv[8];
  if (live) {
    const float4* xr = (const float4*)(x + (size_t)n * FIN + j * 32);
#pragma unroll
    for (int m = 0; m < 8; ++m) xv[m] = xr[m];
  } else {
#pragma unroll
    for (int m = 0; m < 8; ++m) xv[m] = make_float4(0.f, 0.f, 0.f, 0.f);
  }

  float acc[32];
  const float* wj = Wl + j * 36;  // j-block base: 36 floats = 144B (16B-aligned)
#pragma unroll 4
  for (int c = 0; c < 32; ++c) {
    const float4* wr = (const float4*)(wj + c * W_ROW);
    float s = 0.f;
#pragma unroll
    for (int m = 0; m < 8; ++m) {
      float4 wv = wr[m];
      s += xv[m].x * wv.x + xv[m].y * wv.y + xv[m].z * wv.z + xv[m].w * wv.w;
    }
    acc[c] = s;
  }

  // reduce the 4 k-quarters of each node (lanes differ in bits 0-1)
#pragma unroll
  for (int c = 0; c < 32; ++c) {
    acc[c] += __shfl_xor(acc[c], 1);
    acc[c] += __shfl_xor(acc[c], 2);
  }
  if (!live) return;

  if (j == 0) {
    uint4 pk;
    pk.x = (unsigned)f2b(acc[0]) | ((unsigned)f2b(acc[1]) << 16);
    pk.y = (unsigned)f2b(acc[2]) | ((unsigned)f2b(acc[3]) << 16);
    pk.z = (unsigned)f2b(acc[4]) | ((unsigned)f2b(acc[5]) << 16);
    pk.w = (unsigned)f2b(acc[6]) | ((unsigned)f2b(acc[7]) << 16);
    *(uint4*)((char*)xw1b + (size_t)n * 32) = pk;
  } else if (j == 1) {
    uint4 pk;
    pk.x = (unsigned)f2b(acc[8]) | ((unsigned)f2b(acc[9]) << 16);
    pk.y = (unsigned)f2b(acc[10]) | ((unsigned)f2b(acc[11]) << 16);
    pk.z = (unsigned)f2b(acc[12]) | ((unsigned)f2b(acc[13]) << 16);
    pk.w = (unsigned)f2b(acc[14]) | ((unsigned)f2b(acc[15]) << 16);
    *(uint4*)((char*)xw1b + (size_t)n * 32 + 16) = pk;
  } else if (j == 2) {
    *(float4*)(xr1 + (size_t)n * 16 + 0) =
        make_float4(acc[16], acc[17], acc[18], acc[19]);
    *(float4*)(xr1 + (size_t)n * 16 + 4) =
        make_float4(acc[20], acc[21], acc[22], acc[23]);
  } else {
    *(float4*)(xr1 + (size_t)n * 16 + 8) =
        make_float4(acc[24], acc[25], acc[26], acc[27]);
    *(float4*)(xr1 + (size_t)n * 16 + 12) =
        make_float4(acc[28], acc[29], acc[30], acc[31]);
  }
}

// ---------------------------------------------------------------------------
// histB: bucket histogram (391 counters) with LDS pre-aggregation.
// ---------------------------------------------------------------------------
__global__ __launch_bounds__(256) void histB_kernel(
    const int* __restrict__ dst, int* __restrict__ bcnt) {
  __shared__ int hc[NBUCK];
  for (int t = threadIdx.x; t < NBUCK; t += 256) hc[t] = 0;
  __syncthreads();
  int base = blockIdx.x * 4096;
#pragma unroll
  for (int k = 0; k < 16; ++k) {
    int e = base + k * 256 + threadIdx.x;
    if (e < NEDGE) atomicAdd(&hc[dst[e] >> 8], 1);
  }
  __syncthreads();
  for (int t = threadIdx.x; t < NBUCK; t += 256) {
    int v = hc[t];
    if (v) atomicAdd(&bcnt[t], v);
  }
}

// ---------------------------------------------------------------------------
// scan: exclusive scan of 391 counts -> boff, gcursor; set sentinels.
// ---------------------------------------------------------------------------
__global__ __launch_bounds__(512) void scan_kernel(
    const int* __restrict__ bcnt, int* __restrict__ boff,
    int* __restrict__ gcursor, int* __restrict__ rowptr) {
  __shared__ int s[512];
  int v = (threadIdx.x < NBUCK) ? bcnt[threadIdx.x] : 0;
  s[threadIdx.x] = v;
  __syncthreads();
  for (int off = 1; off < 512; off <<= 1) {
    int t = (threadIdx.x >= off) ? s[threadIdx.x - off] : 0;
    __syncthreads();
    s[threadIdx.x] += t;
    __syncthreads();
  }
  if (threadIdx.x < NBUCK) {
    int e = s[threadIdx.x] - v;
    boff[threadIdx.x] = e;
    gcursor[threadIdx.x] = e;
  }
  if (threadIdx.x == 0) {
    boff[NBUCK] = NEDGE;
    rowptr[N_NODES] = NEDGE;
  }
}

// ---------------------------------------------------------------------------
// partA: multi-split partition, 4096-edge chunks.
// rec = src | (dst&255)<<17.
// ---------------------------------------------------------------------------
__global__ __launch_bounds__(256) void partA_kernel(
    const int* __restrict__ src, const int* __restrict__ dst,
    int* __restrict__ gcursor, unsigned* __restrict__ recs) {
  __shared__ int cnt[NBUCK];
  __shared__ int base[NBUCK];
  for (int t = threadIdx.x; t < NBUCK; t += 256) cnt[t] = 0;
  __syncthreads();

  int ebase = blockIdx.x * 4096;
  unsigned recv[16];
  int bk[16];
  int rank[16];
#pragma unroll
  for (int k = 0; k < 16; ++k) {
    int e = ebase + k * 256 + threadIdx.x;
    if (e < NEDGE) {
      int d = dst[e];
      bk[k] = d >> 8;
      recv[k] = (unsigned)src[e] | ((unsigned)(d & 255) << 17);
      rank[k] = atomicAdd(&cnt[bk[k]], 1);
    } else {
      bk[k] = -1;
    }
  }
  __syncthreads();
  for (int t = threadIdx.x; t < NBUCK; t += 256) {
    int cv = cnt[t];
    base[t] = cv ? atomicAdd(&gcursor[t], cv) : 0;
  }
  __syncthreads();
#pragma unroll
  for (int k = 0; k < 16; ++k)
    if (bk[k] >= 0) recs[base[bk[k]] + rank[k]] = recv[k];
}

// ---------------------------------------------------------------------------
// sortB: per-bucket counting sort -> full dst-sorted CSR (rowptr + colsrc).
// ---------------------------------------------------------------------------
__global__ __launch_bounds__(512) void sortB_kernel(
    const int* __restrict__ boff, const unsigned* __restrict__ recs,
    int* __restrict__ rowptr, int* __restrict__ colsrc) {
  __shared__ int hist[256];
  __shared__ int s[256];
  __shared__ int cur[256];
  if (threadIdx.x < 256) hist[threadIdx.x] = 0;
  __syncthreads();

  int b = blockIdx.x;
  int beg = boff[b], end = boff[b + 1];
  for (int j = beg + threadIdx.x; j < end; j += 512)
    atomicAdd(&hist[recs[j] >> 17], 1);
  __syncthreads();

  if (threadIdx.x < 256) s[threadIdx.x] = hist[threadIdx.x];
  __syncthreads();
  for (int off = 1; off < 256; off <<= 1) {
    int t = 0;
    if (threadIdx.x < 256 && threadIdx.x >= off) t = s[threadIdx.x - off];
    __syncthreads();
    if (threadIdx.x < 256) s[threadIdx.x] += t;
    __syncthreads();
  }
  if (threadIdx.x < 256) {
    int excl = s[threadIdx.x] - hist[threadIdx.x];
    int n = b * 256 + threadIdx.x;
    if (n < N_NODES) rowptr[n] = beg + excl;
    cur[threadIdx.x] = excl;
  }
  __syncthreads();

  for (int j = beg + threadIdx.x; j < end; j += 512) {
    unsigned r = recs[j];
    int dl = r >> 17;
    int pos = atomicAdd(&cur[dl], 1);
    colsrc[beg + pos] = (int)(r & 0x1FFFF);
  }
}

// ---------------------------------------------------------------------------
// gather1: 8 lanes/node, bf16 val table (ushort4 = 8B per lane, 32B/edge).
// 3.2MB table fits per-XCD L2 -> random gathers are L2 hits.
// Accumulation fp32. Fused mean + xr1 + b1 + ELU -> h (fp32) AND hb (bf16).
// ---------------------------------------------------------------------------
__global__ __launch_bounds__(256) void gather1_kernel(
    const int* __restrict__ rowptr, const int* __restrict__ colsrc,
    const ushort4* __restrict__ valb4, const float4* __restrict__ xr14,
    const float* __restrict__ b1, float4* __restrict__ h4,
    ushort4* __restrict__ hb4) {
  int t = blockIdx.x * 256 + threadIdx.x;
  int n = t >> 3;
  if (n >= N_NODES) return;
  int q = t & 3;
  int p = (t >> 2) & 1;
  int beg = rowptr[n], end = rowptr[n + 1];

  float4 acc = make_float4(0.f, 0.f, 0.f, 0.f);
  int bA = (beg + 3) & ~3;
  int eA = end & ~3;
  if (bA > eA) {
    if (p == 0)
      for (int j = beg; j < end; ++j)
        acc = f4add(acc, b2f4(valb4[colsrc[j] * 4 + q]));
  } else {
    if (p == 0) {
      for (int j = beg; j < bA; ++j)
        acc = f4add(acc, b2f4(valb4[colsrc[j] * 4 + q]));
    } else {
      for (int j = eA; j < end; ++j)
        acc = f4add(acc, b2f4(valb4[colsrc[j] * 4 + q]));
    }
    float4 acc1 = make_float4(0.f, 0.f, 0.f, 0.f);
    int j = bA + p * 4;
    for (; j + 12 <= eA; j += 16) {
      v4i c0 = __builtin_nontemporal_load((const v4i*)(colsrc + j));
      v4i c1 = __builtin_nontemporal_load((const v4i*)(colsrc + j + 8));
      ushort4 v0 = valb4[c0.x * 4 + q];
      ushort4 v1 = valb4[c0.y * 4 + q];
      ushort4 v2 = valb4[c0.z * 4 + q];
      ushort4 v3 = valb4[c0.w * 4 + q];
      ushort4 v4v = valb4[c1.x * 4 + q];
      ushort4 v5 = valb4[c1.y * 4 + q];
      ushort4 v6 = valb4[c1.z * 4 + q];
      ushort4 v7 = valb4[c1.w * 4 + q];
      acc = f4add(acc, f4add(f4add(b2f4(v0), b2f4(v1)),
                             f4add(b2f4(v2), b2f4(v3))));
      acc1 = f4add(acc1, f4add(f4add(b2f4(v4v), b2f4(v5)),
                               f4add(b2f4(v6), b2f4(v7))));
    }
    for (; j + 4 <= eA; j += 8) {
      v4i c0 = __builtin_nontemporal_load((const v4i*)(colsrc + j));
      ushort4 v0 = valb4[c0.x * 4 + q];
      ushort4 v1 = valb4[c0.y * 4 + q];
      ushort4 v2 = valb4[c0.z * 4 + q];
      ushort4 v3 = valb4[c0.w * 4 + q];
      acc = f4add(acc, f4add(f4add(b2f4(v0), b2f4(v1)),
                             f4add(b2f4(v2), b2f4(v3))));
    }
    acc = f4add(acc, acc1);
  }

  acc.x += __shfl_xor(acc.x, 4);
  acc.y += __shfl_xor(acc.y, 4);
  acc.z += __shfl_xor(acc.z, 4);
  acc.w += __shfl_xor(acc.w, 4);
  if (p) return;

  float inv = 1.0f / fmaxf((float)(end - beg), 1.0f);
  float4 r = xr14[n * 4 + q];
  const float4 bb = *(const float4*)(b1 + q * 4);
  float4 o;
  o.x = acc.x * inv + r.x + bb.x;
  o.y = acc.y * inv + r.y + bb.y;
  o.z = acc.z * inv + r.z + bb.z;
  o.w = acc.w * inv + r.w + bb.w;
  o.x = (o.x > 0.f) ? o.x : expm1f(o.x);
  o.y = (o.y > 0.f) ? o.y : expm1f(o.y);
  o.z = (o.z > 0.f) ? o.z : expm1f(o.z);
  o.w = (o.w > 0.f) ? o.w : expm1f(o.w);
  h4[n * 4 + q] = o;
  ushort4 ob;
  ob.x = f2b(o.x);
  ob.y = f2b(o.y);
  ob.z = f2b(o.z);
  ob.w = f2b(o.w);
  hb4[n * 4 + q] = ob;
}

// ---------------------------------------------------------------------------
// gather2: same structure over hb (bf16); writes mean-normalized agg2n.
// ---------------------------------------------------------------------------
__global__ __launch_bounds__(256) void gather2_kernel(
    const int* __restrict__ rowptr, const int* __restrict__ colsrc,
    const ushort4* __restrict__ valb4, float4* __restrict__ agg2n4) {
  int t = blockIdx.x * 256 + threadIdx.x;
  int n = t >> 3;
  if (n >= N_NODES) return;
  int q = t & 3;
  int p = (t >> 2) & 1;
  int beg = rowptr[n], end = rowptr[n + 1];

  float4 acc = make_float4(0.f, 0.f, 0.f, 0.f);
  int bA = (beg + 3) & ~3;
  int eA = end & ~3;
  if (bA > eA) {
    if (p == 0)
      for (int j = beg; j < end; ++j)
        acc = f4add(acc, b2f4(valb4[colsrc[j] * 4 + q]));
  } else {
    if (p == 0) {
      for (int j = beg; j < bA; ++j)
        acc = f4add(acc, b2f4(valb4[colsrc[j] * 4 + q]));
    } else {
      for (int j = eA; j < end; ++j)
        acc = f4add(acc, b2f4(valb4[colsrc[j] * 4 + q]));
    }
    float4 acc1 = make_float4(0.f, 0.f, 0.f, 0.f);
    int j = bA + p * 4;
    for (; j + 12 <= eA; j += 16) {
      v4i c0 = __builtin_nontemporal_load((const v4i*)(colsrc + j));
      v4i c1 = __builtin_nontemporal_load((const v4i*)(colsrc + j + 8));
      ushort4 v0 = valb4[c0.x * 4 + q];
      ushort4 v1 = valb4[c0.y * 4 + q];
      ushort4 v2 = valb4[c0.z * 4 + q];
      ushort4 v3 = valb4[c0.w * 4 + q];
      ushort4 v4v = valb4[c1.x * 4 + q];
      ushort4 v5 = valb4[c1.y * 4 + q];
      ushort4 v6 = valb4[c1.z * 4 + q];
      ushort4 v7 = valb4[c1.w * 4 + q];
      acc = f4add(acc, f4add(f4add(b2f4(v0), b2f4(v1)),
                             f4add(b2f4(v2), b2f4(v3))));
      acc1 = f4add(acc1, f4add(f4add(b2f4(v4v), b2f4(v5)),
                               f4add(b2f4(v6), b2f4(v7))));
    }
    for (; j + 4 <= eA; j += 8) {
      v4i c0 = __builtin_nontemporal_load((const v4i*)(colsrc + j));
      ushort4 v0 = valb4[c0.x * 4 + q];
      ushort4 v1 = valb4[c0.y * 4 + q];
      ushort4 v2 = valb4[c0.z * 4 + q];
      ushort4 v3 = valb4[c0.w * 4 + q];
      acc = f4add(acc, f4add(f4add(b2f4(v0), b2f4(v1)),
                             f4add(b2f4(v2), b2f4(v3))));
    }
    acc = f4add(acc, acc1);
  }

  acc.x += __shfl_xor(acc.x, 4);
  acc.y += __shfl_xor(acc.y, 4);
  acc.z += __shfl_xor(acc.z, 4);
  acc.w += __shfl_xor(acc.w, 4);
  if (p) return;

  float inv = 1.0f / fmaxf((float)(end - beg), 1.0f);
  agg2n4[n * 4 + q] = make_float4(acc.x * inv, acc.y * inv, acc.z * inv,
                                  acc.w * inv);
}

// ---------------------------------------------------------------------------
// out: agg2n @ W2[1] + h @ root2 + b2, log_softmax, fp32 store.
// ---------------------------------------------------------------------------
__global__ __launch_bounds__(256) void out_kernel(
    const float* __restrict__ h, const float* __restrict__ agg2n,
    const float* __restrict__ W2, const float* __restrict__ root2,
    const float* __restrict__ b2v, float* __restrict__ out) {
  __shared__ float Wl[HID * NCLS];
  __shared__ float Rl[HID * NCLS];
  __shared__ float Bl[NCLS];
  for (int i = threadIdx.x; i < HID * NCLS; i += blockDim.x) {
    Wl[i] = W2[HID * NCLS + i];
    Rl[i] = root2[i];
  }
  if (threadIdx.x < NCLS) Bl[threadIdx.x] = b2v[threadIdx.x];
  __syncthreads();

  int n = blockIdx.x * blockDim.x + threadIdx.x;
  if (n >= N_NODES) return;

  float hv[HID], av[HID];
#pragma unroll
  for (int c = 0; c < HID; ++c) {
    hv[c] = h[n * HID + c];
    av[c] = agg2n[n * HID + c];
  }
  float logit[NCLS];
#pragma unroll
  for (int j = 0; j < NCLS; ++j) logit[j] = Bl[j];
  for (int c = 0; c < HID; ++c) {
    float hc = hv[c], ac = av[c];
#pragma unroll
    for (int j = 0; j < NCLS; ++j)
      logit[j] += ac * Wl[c * NCLS + j] + hc * Rl[c * NCLS + j];
  }
  float m = -INFINITY;
#pragma unroll
  for (int j = 0; j < NCLS; ++j) m = fmaxf(m, logit[j]);
  float s = 0.f;
#pragma unroll
  for (int j = 0; j < NCLS; ++j) s += expf(logit[j] - m);
  float lse = m + logf(s);
#pragma unroll
  for (int j = 0; j < NCLS; ++j)
    out[(size_t)n * NCLS + j] = logit[j] - lse;
}

extern "C" void kernel_launch(void* const* d_in, const int* in_sizes, int n_in,
                              void* d_out, int out_size, void* d_ws,
                              size_t ws_size, hipStream_t stream) {
  const float* x = (const float*)d_in[0];
  const int* ei = (const int*)d_in[1];  // (2, E): src row then dst row
  const float* W1 = (const float*)d_in[2];
  const float* root1 = (const float*)d_in[3];
  const float* b1 = (const float*)d_in[4];
  const float* W2 = (const float*)d_in[5];
  const float* root2 = (const float*)d_in[6];
  const float* b2v = (const float*)d_in[7];
  float* out = (float*)d_out;

  const int* src = ei;
  const int* dstp = ei + NEDGE;

  // workspace (bytes):
  // [bcnt 2K][boff 2K][gcursor 2K][rowptr (N+4)*4]
  // [recs E*4  (lower half reused as h fp32, upper half as agg2n fp32)]
  // [colsrc E*4][xw1b 16N*2][xr1 16N*4][hb 16N*2]
  char* w = (char*)d_ws;
  int* bcnt = (int*)w;           w += 2048;
  int* boff = (int*)w;           w += 2048;
  int* gcursor = (int*)w;        w += 2048;
  int* rowptr = (int*)w;         w += (size_t)(N_NODES + 4) * 4;
  unsigned* recs = (unsigned*)w; w += (size_t)NEDGE * 4;
  int* colsrc = (int*)w;         w += (size_t)NEDGE * 4;
  unsigned* xw1b = (unsigned*)w; w += (size_t)N_NODES * HID * 2;
  float* xr1 = (float*)w;        w += (size_t)N_NODES * HID * 4;
  unsigned short* hb = (unsigned short*)w; w += (size_t)N_NODES * HID * 2;

  float* h = (float*)recs;  // recs dead after sortB; h = 6.4MB (half of recs)
  float* agg2n = (float*)((char*)recs + (size_t)N_NODES * HID * 4);

  hipMemsetAsync(bcnt, 0, 2048, stream);

  proj1_kernel<<<(N_NODES + 63) / 64, 256, 0, stream>>>(x, W1, root1, xw1b,
                                                        xr1);
  histB_kernel<<<NCHUNK, 256, 0, stream>>>(dstp, bcnt);
  scan_kernel<<<1, 512, 0, stream>>>(bcnt, boff, gcursor, rowptr);
  partA_kernel<<<NCHUNK, 256, 0, stream>>>(src, dstp, gcursor, recs);
  sortB_kernel<<<NBUCK, 512, 0, stream>>>(boff, recs, rowptr, colsrc);
  gather1_kernel<<<(N_NODES * 8 + 255) / 256, 256, 0, stream>>>(
      rowptr, colsrc, (const ushort4*)xw1b, (const float4*)xr1, b1, (float4*)h,
      (ushort4*)hb);
  gather2_kernel<<<(N_NODES * 8 + 255) / 256, 256, 0, stream>>>(
      rowptr, colsrc, (const ushort4*)hb, (float4*)agg2n);
  out_kernel<<<(N_NODES + 255) / 256, 256, 0, stream>>>(h, agg2n, W2, root2,
                                                        b2v, out);
}

// Round 4
// 299.608 us; speedup vs baseline: 1.2025x; 1.0114x over previous
//
#include <hip/hip_runtime.h>
#include <hip/hip_bf16.h>

#define N_NODES 100000
#define FIN 128
#define HID 16
#define NCLS 40
#define NEDGE 3200000
#define NBUCK 391     // ceil(100000/256): 256 dst-nodes per bucket
#define NCHUNK 782    // ceil(NEDGE/4096)
#define W_ROW 144     // swizzled W row stride (floats)

typedef int v4i __attribute__((ext_vector_type(4)));

__device__ __forceinline__ float4 f4add(float4 a, float4 b) {
  return make_float4(a.x + b.x, a.y + b.y, a.z + b.z, a.w + b.w);
}

// f32 -> bf16 (RNE)
__device__ __forceinline__ unsigned short f2b(float f) {
  union { float f; unsigned u; } v;
  v.f = f;
  unsigned r = v.u + 0x7FFFu + ((v.u >> 16) & 1u);
  return (unsigned short)(r >> 16);
}

// 4x bf16 -> float4 (shift<<16)
__device__ __forceinline__ float4 b2f4(ushort4 u) {
  union { unsigned u; float f; } a, b, c, d;
  a.u = (unsigned)u.x << 16;
  b.u = (unsigned)u.y << 16;
  c.u = (unsigned)u.z << 16;
  d.u = (unsigned)u.w << 16;
  return make_float4(a.f, b.f, c.f, d.f);
}

// ---------------------------------------------------------------------------
// proj1: 4 lanes per node, no x LDS staging, W in bank-swizzled LDS,
// shfl_xor butterfly + static-index stores. (R12 structure, ~15 us)
// ---------------------------------------------------------------------------
__global__ __launch_bounds__(256) void proj1_kernel(
    const float* __restrict__ x, const float* __restrict__ W1,
    const float* __restrict__ root1,
    unsigned* __restrict__ xw1b, float* __restrict__ xr1) {
  __shared__ float Wl[32 * W_ROW];  // 18.4 KB

  int tid = threadIdx.x;
  for (int t = tid; t < 32 * FIN; t += 256) {
    int c = t >> 7, k = t & 127;
    float v = (c < 16) ? W1[FIN * HID + k * HID + c] : root1[k * HID + (c - 16)];
    Wl[c * W_ROW + k + ((k >> 5) << 2)] = v;
  }
  __syncthreads();

  int n = blockIdx.x * 64 + (tid >> 2);
  int j = tid & 3;
  bool live = (n < N_NODES);

  float4 xv[8];
  if (live) {
    const float4* xr = (const float4*)(x + (size_t)n * FIN + j * 32);
#pragma unroll
    for (int m = 0; m < 8; ++m) xv[m] = xr[m];
  } else {
#pragma unroll
    for (int m = 0; m < 8; ++m) xv[m] = make_float4(0.f, 0.f, 0.f, 0.f);
  }

  float acc[32];
  const float* wj = Wl + j * 36;
#pragma unroll 4
  for (int c = 0; c < 32; ++c) {
    const float4* wr = (const float4*)(wj + c * W_ROW);
    float s = 0.f;
#pragma unroll
    for (int m = 0; m < 8; ++m) {
      float4 wv = wr[m];
      s += xv[m].x * wv.x + xv[m].y * wv.y + xv[m].z * wv.z + xv[m].w * wv.w;
    }
    acc[c] = s;
  }

#pragma unroll
  for (int c = 0; c < 32; ++c) {
    acc[c] += __shfl_xor(acc[c], 1);
    acc[c] += __shfl_xor(acc[c], 2);
  }
  if (!live) return;

  if (j == 0) {
    uint4 pk;
    pk.x = (unsigned)f2b(acc[0]) | ((unsigned)f2b(acc[1]) << 16);
    pk.y = (unsigned)f2b(acc[2]) | ((unsigned)f2b(acc[3]) << 16);
    pk.z = (unsigned)f2b(acc[4]) | ((unsigned)f2b(acc[5]) << 16);
    pk.w = (unsigned)f2b(acc[6]) | ((unsigned)f2b(acc[7]) << 16);
    *(uint4*)((char*)xw1b + (size_t)n * 32) = pk;
  } else if (j == 1) {
    uint4 pk;
    pk.x = (unsigned)f2b(acc[8]) | ((unsigned)f2b(acc[9]) << 16);
    pk.y = (unsigned)f2b(acc[10]) | ((unsigned)f2b(acc[11]) << 16);
    pk.z = (unsigned)f2b(acc[12]) | ((unsigned)f2b(acc[13]) << 16);
    pk.w = (unsigned)f2b(acc[14]) | ((unsigned)f2b(acc[15]) << 16);
    *(uint4*)((char*)xw1b + (size_t)n * 32 + 16) = pk;
  } else if (j == 2) {
    *(float4*)(xr1 + (size_t)n * 16 + 0) =
        make_float4(acc[16], acc[17], acc[18], acc[19]);
    *(float4*)(xr1 + (size_t)n * 16 + 4) =
        make_float4(acc[20], acc[21], acc[22], acc[23]);
  } else {
    *(float4*)(xr1 + (size_t)n * 16 + 8) =
        make_float4(acc[24], acc[25], acc[26], acc[27]);
    *(float4*)(xr1 + (size_t)n * 16 + 12) =
        make_float4(acc[28], acc[29], acc[30], acc[31]);
  }
}

// ---------------------------------------------------------------------------
// R13 histB: 512 threads, 8 edges/thread (same 4096-edge chunks).
// Occupancy fix: 3 blocks/CU x 8 waves = 24 waves/CU (was 12).
// ---------------------------------------------------------------------------
__global__ __launch_bounds__(512) void histB_kernel(
    const int* __restrict__ dst, int* __restrict__ bcnt) {
  __shared__ int hc[NBUCK];
  for (int t = threadIdx.x; t < NBUCK; t += 512) hc[t] = 0;
  __syncthreads();
  int base = blockIdx.x * 4096;
#pragma unroll
  for (int k = 0; k < 8; ++k) {
    int e = base + k * 512 + threadIdx.x;
    if (e < NEDGE) atomicAdd(&hc[dst[e] >> 8], 1);
  }
  __syncthreads();
  for (int t = threadIdx.x; t < NBUCK; t += 512) {
    int v = hc[t];
    if (v) atomicAdd(&bcnt[t], v);
  }
}

// ---------------------------------------------------------------------------
// scan: exclusive scan of 391 counts -> boff, gcursor; set sentinels.
// ---------------------------------------------------------------------------
__global__ __launch_bounds__(512) void scan_kernel(
    const int* __restrict__ bcnt, int* __restrict__ boff,
    int* __restrict__ gcursor, int* __restrict__ rowptr) {
  __shared__ int s[512];
  int v = (threadIdx.x < NBUCK) ? bcnt[threadIdx.x] : 0;
  s[threadIdx.x] = v;
  __syncthreads();
  for (int off = 1; off < 512; off <<= 1) {
    int t = (threadIdx.x >= off) ? s[threadIdx.x - off] : 0;
    __syncthreads();
    s[threadIdx.x] += t;
    __syncthreads();
  }
  if (threadIdx.x < NBUCK) {
    int e = s[threadIdx.x] - v;
    boff[threadIdx.x] = e;
    gcursor[threadIdx.x] = e;
  }
  if (threadIdx.x == 0) {
    boff[NBUCK] = NEDGE;
    rowptr[N_NODES] = NEDGE;
  }
}

// ---------------------------------------------------------------------------
// R13 partA: 512 threads, 8 edges/thread, same 4096-edge chunks (write-run
// coalescing unchanged). Occupancy 20.6% -> ~55%. rec = src | (dst&255)<<17.
// ---------------------------------------------------------------------------
__global__ __launch_bounds__(512) void partA_kernel(
    const int* __restrict__ src, const int* __restrict__ dst,
    int* __restrict__ gcursor, unsigned* __restrict__ recs) {
  __shared__ int cnt[NBUCK];
  __shared__ int base[NBUCK];
  for (int t = threadIdx.x; t < NBUCK; t += 512) cnt[t] = 0;
  __syncthreads();

  int ebase = blockIdx.x * 4096;
  unsigned recv[8];
  int bk[8];
  int rank[8];
#pragma unroll
  for (int k = 0; k < 8; ++k) {
    int e = ebase + k * 512 + threadIdx.x;
    if (e < NEDGE) {
      int d = dst[e];
      bk[k] = d >> 8;
      recv[k] = (unsigned)src[e] | ((unsigned)(d & 255) << 17);
      rank[k] = atomicAdd(&cnt[bk[k]], 1);
    } else {
      bk[k] = -1;
    }
  }
  __syncthreads();
  for (int t = threadIdx.x; t < NBUCK; t += 512) {
    int cv = cnt[t];
    base[t] = cv ? atomicAdd(&gcursor[t], cv) : 0;
  }
  __syncthreads();
#pragma unroll
  for (int k = 0; k < 8; ++k)
    if (bk[k] >= 0) recs[base[bk[k]] + rank[k]] = recv[k];
}

// ---------------------------------------------------------------------------
// R13 sortB: 1024 threads/block (16 waves; up to 32 waves/CU resident).
// Per-bucket counting sort -> full dst-sorted CSR (rowptr + colsrc).
// ---------------------------------------------------------------------------
__global__ __launch_bounds__(1024) void sortB_kernel(
    const int* __restrict__ boff, const unsigned* __restrict__ recs,
    int* __restrict__ rowptr, int* __restrict__ colsrc) {
  __shared__ int hist[256];
  __shared__ int s[256];
  __shared__ int cur[256];
  if (threadIdx.x < 256) hist[threadIdx.x] = 0;
  __syncthreads();

  int b = blockIdx.x;
  int beg = boff[b], end = boff[b + 1];
  for (int j = beg + threadIdx.x; j < end; j += 1024)
    atomicAdd(&hist[recs[j] >> 17], 1);
  __syncthreads();

  if (threadIdx.x < 256) s[threadIdx.x] = hist[threadIdx.x];
  __syncthreads();
  for (int off = 1; off < 256; off <<= 1) {
    int t = 0;
    if (threadIdx.x < 256 && threadIdx.x >= off) t = s[threadIdx.x - off];
    __syncthreads();
    if (threadIdx.x < 256) s[threadIdx.x] += t;
    __syncthreads();
  }
  if (threadIdx.x < 256) {
    int excl = s[threadIdx.x] - hist[threadIdx.x];
    int n = b * 256 + threadIdx.x;
    if (n < N_NODES) rowptr[n] = beg + excl;
    cur[threadIdx.x] = excl;
  }
  __syncthreads();

  for (int j = beg + threadIdx.x; j < end; j += 1024) {
    unsigned r = recs[j];
    int dl = r >> 17;
    int pos = atomicAdd(&cur[dl], 1);
    colsrc[beg + pos] = (int)(r & 0x1FFFF);
  }
}

// ---------------------------------------------------------------------------
// gather1: 8 lanes/node, bf16 val table (ushort4 = 8B per lane, 32B/edge).
// Accumulation fp32. Fused mean + xr1 + b1 + ELU -> h (fp32) AND hb (bf16).
// ---------------------------------------------------------------------------
__global__ __launch_bounds__(256) void gather1_kernel(
    const int* __restrict__ rowptr, const int* __restrict__ colsrc,
    const ushort4* __restrict__ valb4, const float4* __restrict__ xr14,
    const float* __restrict__ b1, float4* __restrict__ h4,
    ushort4* __restrict__ hb4) {
  int t = blockIdx.x * 256 + threadIdx.x;
  int n = t >> 3;
  if (n >= N_NODES) return;
  int q = t & 3;
  int p = (t >> 2) & 1;
  int beg = rowptr[n], end = rowptr[n + 1];

  float4 acc = make_float4(0.f, 0.f, 0.f, 0.f);
  int bA = (beg + 3) & ~3;
  int eA = end & ~3;
  if (bA > eA) {
    if (p == 0)
      for (int j = beg; j < end; ++j)
        acc = f4add(acc, b2f4(valb4[colsrc[j] * 4 + q]));
  } else {
    if (p == 0) {
      for (int j = beg; j < bA; ++j)
        acc = f4add(acc, b2f4(valb4[colsrc[j] * 4 + q]));
    } else {
      for (int j = eA; j < end; ++j)
        acc = f4add(acc, b2f4(valb4[colsrc[j] * 4 + q]));
    }
    float4 acc1 = make_float4(0.f, 0.f, 0.f, 0.f);
    int j = bA + p * 4;
    for (; j + 12 <= eA; j += 16) {
      v4i c0 = __builtin_nontemporal_load((const v4i*)(colsrc + j));
      v4i c1 = __builtin_nontemporal_load((const v4i*)(colsrc + j + 8));
      ushort4 v0 = valb4[c0.x * 4 + q];
      ushort4 v1 = valb4[c0.y * 4 + q];
      ushort4 v2 = valb4[c0.z * 4 + q];
      ushort4 v3 = valb4[c0.w * 4 + q];
      ushort4 v4v = valb4[c1.x * 4 + q];
      ushort4 v5 = valb4[c1.y * 4 + q];
      ushort4 v6 = valb4[c1.z * 4 + q];
      ushort4 v7 = valb4[c1.w * 4 + q];
      acc = f4add(acc, f4add(f4add(b2f4(v0), b2f4(v1)),
                             f4add(b2f4(v2), b2f4(v3))));
      acc1 = f4add(acc1, f4add(f4add(b2f4(v4v), b2f4(v5)),
                               f4add(b2f4(v6), b2f4(v7))));
    }
    for (; j + 4 <= eA; j += 8) {
      v4i c0 = __builtin_nontemporal_load((const v4i*)(colsrc + j));
      ushort4 v0 = valb4[c0.x * 4 + q];
      ushort4 v1 = valb4[c0.y * 4 + q];
      ushort4 v2 = valb4[c0.z * 4 + q];
      ushort4 v3 = valb4[c0.w * 4 + q];
      acc = f4add(acc, f4add(f4add(b2f4(v0), b2f4(v1)),
                             f4add(b2f4(v2), b2f4(v3))));
    }
    acc = f4add(acc, acc1);
  }

  acc.x += __shfl_xor(acc.x, 4);
  acc.y += __shfl_xor(acc.y, 4);
  acc.z += __shfl_xor(acc.z, 4);
  acc.w += __shfl_xor(acc.w, 4);
  if (p) return;

  float inv = 1.0f / fmaxf((float)(end - beg), 1.0f);
  float4 r = xr14[n * 4 + q];
  const float4 bb = *(const float4*)(b1 + q * 4);
  float4 o;
  o.x = acc.x * inv + r.x + bb.x;
  o.y = acc.y * inv + r.y + bb.y;
  o.z = acc.z * inv + r.z + bb.z;
  o.w = acc.w * inv + r.w + bb.w;
  o.x = (o.x > 0.f) ? o.x : expm1f(o.x);
  o.y = (o.y > 0.f) ? o.y : expm1f(o.y);
  o.z = (o.z > 0.f) ? o.z : expm1f(o.z);
  o.w = (o.w > 0.f) ? o.w : expm1f(o.w);
  h4[n * 4 + q] = o;
  ushort4 ob;
  ob.x = f2b(o.x);
  ob.y = f2b(o.y);
  ob.z = f2b(o.z);
  ob.w = f2b(o.w);
  hb4[n * 4 + q] = ob;
}

// ---------------------------------------------------------------------------
// gather2: same structure over hb (bf16); writes mean-normalized agg2n.
// ---------------------------------------------------------------------------
__global__ __launch_bounds__(256) void gather2_kernel(
    const int* __restrict__ rowptr, const int* __restrict__ colsrc,
    const ushort4* __restrict__ valb4, float4* __restrict__ agg2n4) {
  int t = blockIdx.x * 256 + threadIdx.x;
  int n = t >> 3;
  if (n >= N_NODES) return;
  int q = t & 3;
  int p = (t >> 2) & 1;
  int beg = rowptr[n], end = rowptr[n + 1];

  float4 acc = make_float4(0.f, 0.f, 0.f, 0.f);
  int bA = (beg + 3) & ~3;
  int eA = end & ~3;
  if (bA > eA) {
    if (p == 0)
      for (int j = beg; j < end; ++j)
        acc = f4add(acc, b2f4(valb4[colsrc[j] * 4 + q]));
  } else {
    if (p == 0) {
      for (int j = beg; j < bA; ++j)
        acc = f4add(acc, b2f4(valb4[colsrc[j] * 4 + q]));
    } else {
      for (int j = eA; j < end; ++j)
        acc = f4add(acc, b2f4(valb4[colsrc[j] * 4 + q]));
    }
    float4 acc1 = make_float4(0.f, 0.f, 0.f, 0.f);
    int j = bA + p * 4;
    for (; j + 12 <= eA; j += 16) {
      v4i c0 = __builtin_nontemporal_load((const v4i*)(colsrc + j));
      v4i c1 = __builtin_nontemporal_load((const v4i*)(colsrc + j + 8));
      ushort4 v0 = valb4[c0.x * 4 + q];
      ushort4 v1 = valb4[c0.y * 4 + q];
      ushort4 v2 = valb4[c0.z * 4 + q];
      ushort4 v3 = valb4[c0.w * 4 + q];
      ushort4 v4v = valb4[c1.x * 4 + q];
      ushort4 v5 = valb4[c1.y * 4 + q];
      ushort4 v6 = valb4[c1.z * 4 + q];
      ushort4 v7 = valb4[c1.w * 4 + q];
      acc = f4add(acc, f4add(f4add(b2f4(v0), b2f4(v1)),
                             f4add(b2f4(v2), b2f4(v3))));
      acc1 = f4add(acc1, f4add(f4add(b2f4(v4v), b2f4(v5)),
                               f4add(b2f4(v6), b2f4(v7))));
    }
    for (; j + 4 <= eA; j += 8) {
      v4i c0 = __builtin_nontemporal_load((const v4i*)(colsrc + j));
      ushort4 v0 = valb4[c0.x * 4 + q];
      ushort4 v1 = valb4[c0.y * 4 + q];
      ushort4 v2 = valb4[c0.z * 4 + q];
      ushort4 v3 = valb4[c0.w * 4 + q];
      acc = f4add(acc, f4add(f4add(b2f4(v0), b2f4(v1)),
                             f4add(b2f4(v2), b2f4(v3))));
    }
    acc = f4add(acc, acc1);
  }

  acc.x += __shfl_xor(acc.x, 4);
  acc.y += __shfl_xor(acc.y, 4);
  acc.z += __shfl_xor(acc.z, 4);
  acc.w += __shfl_xor(acc.w, 4);
  if (p) return;

  float inv = 1.0f / fmaxf((float)(end - beg), 1.0f);
  agg2n4[n * 4 + q] = make_float4(acc.x * inv, acc.y * inv, acc.z * inv,
                                  acc.w * inv);
}

// ---------------------------------------------------------------------------
// out: agg2n @ W2[1] + h @ root2 + b2, log_softmax, fp32 store.
// ---------------------------------------------------------------------------
__global__ __launch_bounds__(256) void out_kernel(
    const float* __restrict__ h, const float* __restrict__ agg2n,
    const float* __restrict__ W2, const float* __restrict__ root2,
    const float* __restrict__ b2v, float* __restrict__ out) {
  __shared__ float Wl[HID * NCLS];
  __shared__ float Rl[HID * NCLS];
  __shared__ float Bl[NCLS];
  for (int i = threadIdx.x; i < HID * NCLS; i += blockDim.x) {
    Wl[i] = W2[HID * NCLS + i];
    Rl[i] = root2[i];
  }
  if (threadIdx.x < NCLS) Bl[threadIdx.x] = b2v[threadIdx.x];
  __syncthreads();

  int n = blockIdx.x * blockDim.x + threadIdx.x;
  if (n >= N_NODES) return;

  float hv[HID], av[HID];
#pragma unroll
  for (int c = 0; c < HID; ++c) {
    hv[c] = h[n * HID + c];
    av[c] = agg2n[n * HID + c];
  }
  float logit[NCLS];
#pragma unroll
  for (int j = 0; j < NCLS; ++j) logit[j] = Bl[j];
  for (int c = 0; c < HID; ++c) {
    float hc = hv[c], ac = av[c];
#pragma unroll
    for (int j = 0; j < NCLS; ++j)
      logit[j] += ac * Wl[c * NCLS + j] + hc * Rl[c * NCLS + j];
  }
  float m = -INFINITY;
#pragma unroll
  for (int j = 0; j < NCLS; ++j) m = fmaxf(m, logit[j]);
  float s = 0.f;
#pragma unroll
  for (int j = 0; j < NCLS; ++j) s += expf(logit[j] - m);
  float lse = m + logf(s);
#pragma unroll
  for (int j = 0; j < NCLS; ++j)
    out[(size_t)n * NCLS + j] = logit[j] - lse;
}

extern "C" void kernel_launch(void* const* d_in, const int* in_sizes, int n_in,
                              void* d_out, int out_size, void* d_ws,
                              size_t ws_size, hipStream_t stream) {
  const float* x = (const float*)d_in[0];
  const int* ei = (const int*)d_in[1];  // (2, E): src row then dst row
  const float* W1 = (const float*)d_in[2];
  const float* root1 = (const float*)d_in[3];
  const float* b1 = (const float*)d_in[4];
  const float* W2 = (const float*)d_in[5];
  const float* root2 = (const float*)d_in[6];
  const float* b2v = (const float*)d_in[7];
  float* out = (float*)d_out;

  const int* src = ei;
  const int* dstp = ei + NEDGE;

  // workspace (bytes):
  // [bcnt 2K][boff 2K][gcursor 2K][rowptr (N+4)*4]
  // [recs E*4  (lower half reused as h fp32, upper half as agg2n fp32)]
  // [colsrc E*4][xw1b 16N*2][xr1 16N*4][hb 16N*2]
  char* w = (char*)d_ws;
  int* bcnt = (int*)w;           w += 2048;
  int* boff = (int*)w;           w += 2048;
  int* gcursor = (int*)w;        w += 2048;
  int* rowptr = (int*)w;         w += (size_t)(N_NODES + 4) * 4;
  unsigned* recs = (unsigned*)w; w += (size_t)NEDGE * 4;
  int* colsrc = (int*)w;         w += (size_t)NEDGE * 4;
  unsigned* xw1b = (unsigned*)w; w += (size_t)N_NODES * HID * 2;
  float* xr1 = (float*)w;        w += (size_t)N_NODES * HID * 4;
  unsigned short* hb = (unsigned short*)w; w += (size_t)N_NODES * HID * 2;

  float* h = (float*)recs;  // recs dead after sortB; h = 6.4MB (half of recs)
  float* agg2n = (float*)((char*)recs + (size_t)N_NODES * HID * 4);

  hipMemsetAsync(bcnt, 0, 2048, stream);

  proj1_kernel<<<(N_NODES + 63) / 64, 256, 0, stream>>>(x, W1, root1, xw1b,
                                                        xr1);
  histB_kernel<<<NCHUNK, 512, 0, stream>>>(dstp, bcnt);
  scan_kernel<<<1, 512, 0, stream>>>(bcnt, boff, gcursor, rowptr);
  partA_kernel<<<NCHUNK, 512, 0, stream>>>(src, dstp, gcursor, recs);
  sortB_kernel<<<NBUCK, 1024, 0, stream>>>(boff, recs, rowptr, colsrc);
  gather1_kernel<<<(N_NODES * 8 + 255) / 256, 256, 0, stream>>>(
      rowptr, colsrc, (const ushort4*)xw1b, (const float4*)xr1, b1, (float4*)h,
      (ushort4*)hb);
  gather2_kernel<<<(N_NODES * 8 + 255) / 256, 256, 0, stream>>>(
      rowptr, colsrc, (const ushort4*)hb, (float4*)agg2n);
  out_kernel<<<(N_NODES + 255) / 256, 256, 0, stream>>>(h, agg2n, W2, root2,
                                                        b2v, out);
}